// Round 1
// baseline (232.033 us; speedup 1.0000x reference)
//
#include <hip/hip_runtime.h>
#include <hip/hip_bf16.h>

typedef __attribute__((ext_vector_type(8))) short bf16x8;
typedef __attribute__((ext_vector_type(4))) float f32x4;

#define D        256
#define NH       512
#define NT       (NH/16)          // 32 n-tiles
#define KT       (D/32)           // 8 k-steps
#define MT       4                // M-tiles (16 rows) per wave
#define WAVES    4
#define ROWS_PER_WAVE  (MT*16)            // 64
#define ROWS_PER_BLOCK (WAVES*ROWS_PER_WAVE) // 256
#define ROWS_TOTAL (32*8192)              // 262144

__device__ __forceinline__ short f2bf(float f) {
    union { float f; unsigned u; } v; v.f = f;
    unsigned r = v.u + 0x7FFFu + ((v.u >> 16) & 1u);
    return (short)(r >> 16);
}

__device__ __forceinline__ float fast_tanh(float x) {
    float e = __expf(2.0f * x);
    return 1.0f - 2.0f / (e + 1.0f);
}

// Pack We (fp32 [256][512]) into bf16 MFMA B-fragments:
// frag[(nt*8+kt)*64 + lane][j] = We[kt*32 + (lane>>4)*8 + j][nt*16 + (lane&15)]
__global__ void prepack_B(const float* __restrict__ We, short* __restrict__ Bh) {
    int i = blockIdx.x * 256 + threadIdx.x;      // 131072 elements
    int k = i >> 9;
    int n = i & 511;
    int nt = n >> 4, c = n & 15;
    int kt = k >> 5, g = (k >> 3) & 3, j = k & 7;
    int idx = (((nt * 8 + kt) * 64) + (g * 16 + c)) * 8 + j;
    Bh[idx] = f2bf(We[i]);
}

__global__ __launch_bounds__(256, 2) void softpool_main(
    const float* __restrict__ x, const short* __restrict__ Bh,
    const float* __restrict__ be, const float* __restrict__ Wr,
    const float* __restrict__ br, float* __restrict__ out)
{
    const int lane = threadIdx.x & 63;
    const int wave = threadIdx.x >> 6;
    const int c = lane & 15;     // A row-in-tile / C col / B col
    const int g = lane >> 4;     // k-group
    const long row0 = (long)blockIdx.x * ROWS_PER_BLOCK + (long)wave * ROWS_PER_WAVE;

    // ---- Load A fragments (4 Mtiles x 8 k-steps), fp32 -> bf16, keep in regs
    bf16x8 a[MT][KT];
    #pragma unroll
    for (int m = 0; m < MT; ++m) {
        const float* xr = x + (row0 + m * 16 + c) * D + g * 8;
        #pragma unroll
        for (int kt = 0; kt < KT; ++kt) {
            float4 v0 = *(const float4*)(xr + kt * 32);
            float4 v1 = *(const float4*)(xr + kt * 32 + 4);
            bf16x8 t;
            t[0] = f2bf(v0.x); t[1] = f2bf(v0.y); t[2] = f2bf(v0.z); t[3] = f2bf(v0.w);
            t[4] = f2bf(v1.x); t[5] = f2bf(v1.y); t[6] = f2bf(v1.z); t[7] = f2bf(v1.w);
            a[m][kt] = t;
        }
    }

    // ---- Main loop over hidden n-tiles: GEMM + fused tanh * Wr partial logits
    float lp[MT][4];
    #pragma unroll
    for (int m = 0; m < MT; ++m)
        #pragma unroll
        for (int r = 0; r < 4; ++r) lp[m][r] = 0.0f;

    for (int nt = 0; nt < NT; ++nt) {
        const short* bp = Bh + ((long)(nt * 8) * 64 + lane) * 8;
        f32x4 acc[MT];
        #pragma unroll
        for (int m = 0; m < MT; ++m)
            #pragma unroll
            for (int r = 0; r < 4; ++r) acc[m][r] = 0.0f;

        #pragma unroll
        for (int kt = 0; kt < KT; ++kt) {
            bf16x8 b = *(const bf16x8*)(bp + kt * 64 * 8);
            #pragma unroll
            for (int m = 0; m < MT; ++m)
                acc[m] = __builtin_amdgcn_mfma_f32_16x16x32_bf16(a[m][kt], b, acc[m], 0, 0, 0);
        }

        int n = nt * 16 + c;
        float bias = be[n];
        float vr   = Wr[n];
        #pragma unroll
        for (int m = 0; m < MT; ++m)
            #pragma unroll
            for (int r = 0; r < 4; ++r)
                lp[m][r] += fast_tanh(acc[m][r] + bias) * vr;
    }

    // ---- Reduce logits across the 16 cols; softmax(sigmoid); weighted output
    const float brv = br[0];
    #pragma unroll
    for (int m = 0; m < MT; ++m) {
        float l0 = lp[m][0], l1 = lp[m][1], l2 = lp[m][2], l3 = lp[m][3];
        #pragma unroll
        for (int off = 1; off < 16; off <<= 1) {
            l0 += __shfl_xor(l0, off, 64);
            l1 += __shfl_xor(l1, off, 64);
            l2 += __shfl_xor(l2, off, 64);
            l3 += __shfl_xor(l3, off, 64);
        }
        // sigmoid(logit + br)
        float s0 = 1.0f / (1.0f + __expf(-(l0 + brv)));
        float s1 = 1.0f / (1.0f + __expf(-(l1 + brv)));
        float s2 = 1.0f / (1.0f + __expf(-(l2 + brv)));
        float s3 = 1.0f / (1.0f + __expf(-(l3 + brv)));
        // softmax over the 4 window positions
        float e0 = __expf(s0), e1 = __expf(s1), e2 = __expf(s2), e3 = __expf(s3);
        float inv = 1.0f / (e0 + e1 + e2 + e3);
        float w0 = e0 * inv, w1 = e1 * inv, w2 = e2 * inv, w3 = e3 * inv;

        // window = rows [wrow, wrow+3]; lane-group g owns window g of this Mtile
        const long wrow = row0 + m * 16 + g * 4;
        const long W = wrow >> 2;
        const float* xw = x + wrow * D + c * 16;
        float* op = out + W * D + c * 16;
        #pragma unroll
        for (int q = 0; q < 4; ++q) {
            float4 r0 = *(const float4*)(xw + 0 * D + q * 4);
            float4 r1 = *(const float4*)(xw + 1 * D + q * 4);
            float4 r2 = *(const float4*)(xw + 2 * D + q * 4);
            float4 r3 = *(const float4*)(xw + 3 * D + q * 4);
            float4 oo;
            oo.x = w0 * r0.x + w1 * r1.x + w2 * r2.x + w3 * r3.x;
            oo.y = w0 * r0.y + w1 * r1.y + w2 * r2.y + w3 * r3.y;
            oo.z = w0 * r0.z + w1 * r1.z + w2 * r2.z + w3 * r3.z;
            oo.w = w0 * r0.w + w1 * r1.w + w2 * r2.w + w3 * r3.w;
            *(float4*)(op + q * 4) = oo;
        }
    }
}

extern "C" void kernel_launch(void* const* d_in, const int* in_sizes, int n_in,
                              void* d_out, int out_size, void* d_ws, size_t ws_size,
                              hipStream_t stream) {
    const float* x  = (const float*)d_in[0];
    const float* We = (const float*)d_in[1];
    const float* be = (const float*)d_in[2];
    const float* Wr = (const float*)d_in[3];
    const float* br = (const float*)d_in[4];
    float* out = (float*)d_out;
    short* Bh  = (short*)d_ws;   // 131072 bf16 = 256 KB

    prepack_B<<<NH * D / 256, 256, 0, stream>>>(We, Bh);

    const int blocks = ROWS_TOTAL / ROWS_PER_BLOCK;   // 1024
    softpool_main<<<blocks, 256, 0, stream>>>(x, Bh, be, Wr, br, out);
}

// Round 2
// 217.043 us; speedup vs baseline: 1.0691x; 1.0691x over previous
//
#include <hip/hip_runtime.h>
#include <hip/hip_bf16.h>

typedef __attribute__((ext_vector_type(8))) short bf16x8;
typedef __attribute__((ext_vector_type(4))) float f32x4;

#define D        256
#define NH       512
#define NT       (NH/16)          // 32 n-tiles
#define KT       (D/32)           // 8 k-steps
#define MT       4                // M-tiles (16 rows) per wave
#define WAVES    4
#define ROWS_PER_WAVE  (MT*16)            // 64
#define ROWS_PER_BLOCK (WAVES*ROWS_PER_WAVE) // 256
#define ROWS_TOTAL (32*8192)              // 262144

__device__ __forceinline__ short f2bf(float f) {
    union { float f; unsigned u; } v; v.f = f;
    unsigned r = v.u + 0x7FFFu + ((v.u >> 16) & 1u);
    return (short)(r >> 16);
}

__device__ __forceinline__ float rcp_fast(float x) {
    return __builtin_amdgcn_rcpf(x);          // v_rcp_f32, no IEEE div sequence
}

__device__ __forceinline__ float tanh_fast(float x) {
    // tanh(x) = 1 - 2/(exp(2x)+1); ~5 VALU ops, 2 transcendental
    float e = __expf(2.0f * x);
    return __builtin_fmaf(-2.0f, rcp_fast(e + 1.0f), 1.0f);
}

// Pack We (fp32 [256][512]) into bf16 MFMA B-fragments:
// frag[(nt*8+kt)*64 + lane][j] = We[kt*32 + (lane>>4)*8 + j][nt*16 + (lane&15)]
__global__ void prepack_B(const float* __restrict__ We, short* __restrict__ Bh) {
    int i = blockIdx.x * 256 + threadIdx.x;      // 131072 elements
    int k = i >> 9;
    int n = i & 511;
    int nt = n >> 4, c = n & 15;
    int kt = k >> 5, g = (k >> 3) & 3, j = k & 7;
    int idx = (((nt * 8 + kt) * 64) + (g * 16 + c)) * 8 + j;
    Bh[idx] = f2bf(We[i]);
}

__global__ __launch_bounds__(256, 2) void softpool_main(
    const float* __restrict__ x, const short* __restrict__ Bh,
    const float* __restrict__ be, const float* __restrict__ Wr,
    const float* __restrict__ br, float* __restrict__ out)
{
    const int lane = threadIdx.x & 63;
    const int wave = threadIdx.x >> 6;
    const int c = lane & 15;     // A row-in-tile / C col / B col
    const int g = lane >> 4;     // k-group
    const long row0 = (long)blockIdx.x * ROWS_PER_BLOCK + (long)wave * ROWS_PER_WAVE;

    const short* bbase = Bh + lane * 8;   // + nt*4096 + kt*512

    // ---- Prefetch B for nt=0 (issued before the A HBM loads)
    bf16x8 bA[KT], bB[KT];
    #pragma unroll
    for (int kt = 0; kt < KT; ++kt)
        bA[kt] = *(const bf16x8*)(bbase + kt * 512);

    // ---- Load A fragments (4 Mtiles x 8 k-steps), fp32 -> bf16, keep in regs
    bf16x8 a[MT][KT];
    #pragma unroll
    for (int m = 0; m < MT; ++m) {
        const float* xr = x + (row0 + m * 16 + c) * D + g * 8;
        #pragma unroll
        for (int kt = 0; kt < KT; ++kt) {
            float4 v0 = *(const float4*)(xr + kt * 32);
            float4 v1 = *(const float4*)(xr + kt * 32 + 4);
            bf16x8 t;
            t[0] = f2bf(v0.x); t[1] = f2bf(v0.y); t[2] = f2bf(v0.z); t[3] = f2bf(v0.w);
            t[4] = f2bf(v1.x); t[5] = f2bf(v1.y); t[6] = f2bf(v1.z); t[7] = f2bf(v1.w);
            a[m][kt] = t;
        }
    }

    float lp[MT][4];
    #pragma unroll
    for (int m = 0; m < MT; ++m)
        #pragma unroll
        for (int r = 0; r < 4; ++r) lp[m][r] = 0.0f;

    // ---- Main loop, 2x unrolled with register double-buffered B prefetch
    #define LDB(dst, ntv) {                                               \
        const short* _p = bbase + (long)(ntv) * 4096;                     \
        _Pragma("unroll")                                                 \
        for (int kt = 0; kt < KT; ++kt)                                   \
            dst[kt] = *(const bf16x8*)(_p + kt * 512);                    \
    }

    #define PROCESS(breg, ntv) {                                          \
        f32x4 acc[MT];                                                    \
        _Pragma("unroll")                                                 \
        for (int m = 0; m < MT; ++m)                                      \
            _Pragma("unroll")                                             \
            for (int r = 0; r < 4; ++r) acc[m][r] = 0.0f;                 \
        _Pragma("unroll")                                                 \
        for (int kt = 0; kt < KT; ++kt)                                   \
            _Pragma("unroll")                                             \
            for (int m = 0; m < MT; ++m)                                  \
                acc[m] = __builtin_amdgcn_mfma_f32_16x16x32_bf16(         \
                             a[m][kt], breg[kt], acc[m], 0, 0, 0);        \
        int n = (ntv) * 16 + c;                                           \
        float bias = be[n];                                               \
        float vr   = Wr[n];                                               \
        _Pragma("unroll")                                                 \
        for (int m = 0; m < MT; ++m)                                      \
            _Pragma("unroll")                                             \
            for (int r = 0; r < 4; ++r)                                   \
                lp[m][r] += tanh_fast(acc[m][r] + bias) * vr;             \
    }

    for (int nt = 0; nt < NT; nt += 2) {
        LDB(bB, nt + 1);
        PROCESS(bA, nt);
        LDB(bA, (nt + 2) & (NT - 1));   // wraps at end: harmless L1-hit reload
        PROCESS(bB, nt + 1);
    }

    // ---- Reduce logits across the 16 cols; softmax(sigmoid); weighted output
    const float brv = br[0];
    #pragma unroll
    for (int m = 0; m < MT; ++m) {
        float l0 = lp[m][0], l1 = lp[m][1], l2 = lp[m][2], l3 = lp[m][3];
        #pragma unroll
        for (int off = 1; off < 16; off <<= 1) {
            l0 += __shfl_xor(l0, off, 64);
            l1 += __shfl_xor(l1, off, 64);
            l2 += __shfl_xor(l2, off, 64);
            l3 += __shfl_xor(l3, off, 64);
        }
        // sigmoid(logit + br)
        float s0 = rcp_fast(1.0f + __expf(-(l0 + brv)));
        float s1 = rcp_fast(1.0f + __expf(-(l1 + brv)));
        float s2 = rcp_fast(1.0f + __expf(-(l2 + brv)));
        float s3 = rcp_fast(1.0f + __expf(-(l3 + brv)));
        // softmax over the 4 window positions (values in (0,1): no max-sub needed)
        float e0 = __expf(s0), e1 = __expf(s1), e2 = __expf(s2), e3 = __expf(s3);
        float inv = rcp_fast(e0 + e1 + e2 + e3);
        float w0 = e0 * inv, w1 = e1 * inv, w2 = e2 * inv, w3 = e3 * inv;

        // window = rows [wrow, wrow+3]; lane-group g owns window g of this Mtile
        // lane writes cols [c*4 + q*64 .. +3]: 16 consecutive lanes -> 256B contiguous
        const long wrow = row0 + m * 16 + g * 4;
        const long W = wrow >> 2;
        const float* xw = x + wrow * D + c * 4;
        float* op = out + W * D + c * 4;
        #pragma unroll
        for (int q = 0; q < 4; ++q) {
            float4 r0 = *(const float4*)(xw + 0 * D + q * 64);
            float4 r1 = *(const float4*)(xw + 1 * D + q * 64);
            float4 r2 = *(const float4*)(xw + 2 * D + q * 64);
            float4 r3 = *(const float4*)(xw + 3 * D + q * 64);
            float4 oo;
            oo.x = w0 * r0.x + w1 * r1.x + w2 * r2.x + w3 * r3.x;
            oo.y = w0 * r0.y + w1 * r1.y + w2 * r2.y + w3 * r3.y;
            oo.z = w0 * r0.z + w1 * r1.z + w2 * r2.z + w3 * r3.z;
            oo.w = w0 * r0.w + w1 * r1.w + w2 * r2.w + w3 * r3.w;
            *(float4*)(op + q * 64) = oo;
        }
    }
}

extern "C" void kernel_launch(void* const* d_in, const int* in_sizes, int n_in,
                              void* d_out, int out_size, void* d_ws, size_t ws_size,
                              hipStream_t stream) {
    const float* x  = (const float*)d_in[0];
    const float* We = (const float*)d_in[1];
    const float* be = (const float*)d_in[2];
    const float* Wr = (const float*)d_in[3];
    const float* br = (const float*)d_in[4];
    float* out = (float*)d_out;
    short* Bh  = (short*)d_ws;   // 131072 bf16 = 256 KB

    prepack_B<<<NH * D / 256, 256, 0, stream>>>(We, Bh);

    const int blocks = ROWS_TOTAL / ROWS_PER_BLOCK;   // 1024
    softpool_main<<<blocks, 256, 0, stream>>>(x, Bh, be, Wr, br, out);
}

// Round 3
// 187.406 us; speedup vs baseline: 1.2381x; 1.1581x over previous
//
#include <hip/hip_runtime.h>
#include <hip/hip_bf16.h>

typedef __attribute__((ext_vector_type(8))) short bf16x8;
typedef __attribute__((ext_vector_type(4))) float f32x4;

#define D        256
#define NH       512
#define NT       (NH/16)          // 32 n-tiles
#define KT       (D/32)           // 8 k-steps
#define MT       2                // M-tiles (16 rows) per wave
#define WAVES    4
#define ROWS_PER_WAVE  (MT*16)            // 32
#define ROWS_PER_BLOCK (WAVES*ROWS_PER_WAVE) // 128
#define ROWS_TOTAL (32*8192)              // 262144

__device__ __forceinline__ short f2bf(float f) {
    union { float f; unsigned u; } v; v.f = f;
    unsigned r = v.u + 0x7FFFu + ((v.u >> 16) & 1u);
    return (short)(r >> 16);
}

__device__ __forceinline__ float rcp_fast(float x) {
    return __builtin_amdgcn_rcpf(x);          // v_rcp_f32, no IEEE div sequence
}

__device__ __forceinline__ float tanh_fast(float x) {
    // tanh(x) = 1 - 2/(exp(2x)+1); ~5 VALU ops, 2 transcendental
    float e = __expf(2.0f * x);
    return __builtin_fmaf(-2.0f, rcp_fast(e + 1.0f), 1.0f);
}

// Pack We (fp32 [256][512]) into bf16 MFMA B-fragments:
// frag[(nt*8+kt)*64 + lane][j] = We[kt*32 + (lane>>4)*8 + j][nt*16 + (lane&15)]
__global__ void prepack_B(const float* __restrict__ We, short* __restrict__ Bh) {
    int i = blockIdx.x * 256 + threadIdx.x;      // 131072 elements
    int k = i >> 9;
    int n = i & 511;
    int nt = n >> 4, c = n & 15;
    int kt = k >> 5, g = (k >> 3) & 3, j = k & 7;
    int idx = (((nt * 8 + kt) * 64) + (g * 16 + c)) * 8 + j;
    Bh[idx] = f2bf(We[i]);
}

// 4 waves/SIMD target: total unified (VGPR+AGPR) regs must be <=128.
// Budget: A frags 64 + B transient ~16 + acc 8 + lp 8 + misc ~25 = ~120.
__global__ __launch_bounds__(256, 4) void softpool_main(
    const float* __restrict__ x, const short* __restrict__ Bh,
    const float* __restrict__ be, const float* __restrict__ Wr,
    const float* __restrict__ br, float* __restrict__ out)
{
    const int lane = threadIdx.x & 63;
    const int wave = threadIdx.x >> 6;
    const int c = lane & 15;     // A row-in-tile / C col / B col
    const int g = lane >> 4;     // k-group
    const long row0 = (long)blockIdx.x * ROWS_PER_BLOCK + (long)wave * ROWS_PER_WAVE;

    const short* bbase = Bh + lane * 8;   // + nt*4096 + kt*512

    // ---- Load A fragments (2 Mtiles x 8 k-steps), fp32 -> bf16, keep in regs
    bf16x8 a[MT][KT];
    #pragma unroll
    for (int m = 0; m < MT; ++m) {
        const float* xr = x + (row0 + m * 16 + c) * D + g * 8;
        #pragma unroll
        for (int kt = 0; kt < KT; ++kt) {
            float4 v0 = *(const float4*)(xr + kt * 32);
            float4 v1 = *(const float4*)(xr + kt * 32 + 4);
            bf16x8 t;
            t[0] = f2bf(v0.x); t[1] = f2bf(v0.y); t[2] = f2bf(v0.z); t[3] = f2bf(v0.w);
            t[4] = f2bf(v1.x); t[5] = f2bf(v1.y); t[6] = f2bf(v1.z); t[7] = f2bf(v1.w);
            a[m][kt] = t;
        }
    }

    float lp[MT][4];
    #pragma unroll
    for (int m = 0; m < MT; ++m)
        #pragma unroll
        for (int r = 0; r < 4; ++r) lp[m][r] = 0.0f;

    // ---- Main loop: B loaded inline per kt (L1/L2-resident, compiler pipelines)
    for (int nt = 0; nt < NT; ++nt) {
        const short* bp = bbase + (long)nt * 4096;
        f32x4 acc[MT];
        #pragma unroll
        for (int m = 0; m < MT; ++m)
            #pragma unroll
            for (int r = 0; r < 4; ++r) acc[m][r] = 0.0f;

        #pragma unroll
        for (int kt = 0; kt < KT; ++kt) {
            bf16x8 b = *(const bf16x8*)(bp + kt * 512);
            #pragma unroll
            for (int m = 0; m < MT; ++m)
                acc[m] = __builtin_amdgcn_mfma_f32_16x16x32_bf16(a[m][kt], b, acc[m], 0, 0, 0);
        }

        int n = nt * 16 + c;
        float bias = be[n];
        float vr   = Wr[n];
        #pragma unroll
        for (int m = 0; m < MT; ++m)
            #pragma unroll
            for (int r = 0; r < 4; ++r)
                lp[m][r] += tanh_fast(acc[m][r] + bias) * vr;
    }

    // ---- Reduce logits across the 16 cols; softmax(sigmoid); weighted output
    const float brv = br[0];
    #pragma unroll
    for (int m = 0; m < MT; ++m) {
        float l0 = lp[m][0], l1 = lp[m][1], l2 = lp[m][2], l3 = lp[m][3];
        #pragma unroll
        for (int off = 1; off < 16; off <<= 1) {
            l0 += __shfl_xor(l0, off, 64);
            l1 += __shfl_xor(l1, off, 64);
            l2 += __shfl_xor(l2, off, 64);
            l3 += __shfl_xor(l3, off, 64);
        }
        // sigmoid(logit + br)
        float s0 = rcp_fast(1.0f + __expf(-(l0 + brv)));
        float s1 = rcp_fast(1.0f + __expf(-(l1 + brv)));
        float s2 = rcp_fast(1.0f + __expf(-(l2 + brv)));
        float s3 = rcp_fast(1.0f + __expf(-(l3 + brv)));
        // softmax over the 4 window positions (values in (0,1): no max-sub needed)
        float e0 = __expf(s0), e1 = __expf(s1), e2 = __expf(s2), e3 = __expf(s3);
        float inv = rcp_fast(e0 + e1 + e2 + e3);
        float w0 = e0 * inv, w1 = e1 * inv, w2 = e2 * inv, w3 = e3 * inv;

        // window = rows [wrow, wrow+3]; lane-group g owns window g of this Mtile
        // lane writes cols [c*4 + q*64 .. +3]: 16 consecutive lanes -> 256B contiguous
        const long wrow = row0 + m * 16 + g * 4;
        const long W = wrow >> 2;
        const float* xw = x + wrow * D + c * 4;
        float* op = out + W * D + c * 4;
        #pragma unroll
        for (int q = 0; q < 4; ++q) {
            float4 r0 = *(const float4*)(xw + 0 * D + q * 64);
            float4 r1 = *(const float4*)(xw + 1 * D + q * 64);
            float4 r2 = *(const float4*)(xw + 2 * D + q * 64);
            float4 r3 = *(const float4*)(xw + 3 * D + q * 64);
            float4 oo;
            oo.x = w0 * r0.x + w1 * r1.x + w2 * r2.x + w3 * r3.x;
            oo.y = w0 * r0.y + w1 * r1.y + w2 * r2.y + w3 * r3.y;
            oo.z = w0 * r0.z + w1 * r1.z + w2 * r2.z + w3 * r3.z;
            oo.w = w0 * r0.w + w1 * r1.w + w2 * r2.w + w3 * r3.w;
            *(float4*)(op + q * 64) = oo;
        }
    }
}

extern "C" void kernel_launch(void* const* d_in, const int* in_sizes, int n_in,
                              void* d_out, int out_size, void* d_ws, size_t ws_size,
                              hipStream_t stream) {
    const float* x  = (const float*)d_in[0];
    const float* We = (const float*)d_in[1];
    const float* be = (const float*)d_in[2];
    const float* Wr = (const float*)d_in[3];
    const float* br = (const float*)d_in[4];
    float* out = (float*)d_out;
    short* Bh  = (short*)d_ws;   // 131072 bf16 = 256 KB

    prepack_B<<<NH * D / 256, 256, 0, stream>>>(We, Bh);

    const int blocks = ROWS_TOTAL / ROWS_PER_BLOCK;   // 2048
    softpool_main<<<blocks, 256, 0, stream>>>(x, Bh, be, Wr, br, out);
}

// Round 4
// 175.926 us; speedup vs baseline: 1.3189x; 1.0653x over previous
//
#include <hip/hip_runtime.h>
#include <hip/hip_bf16.h>

typedef __attribute__((ext_vector_type(8))) short bf16x8;
typedef __attribute__((ext_vector_type(4))) float f32x4;

#define D        256
#define NH       512
#define NT       (NH/16)          // 32 n-tiles
#define KT       (D/32)           // 8 k-steps
#define MT       2                // M-tiles (16 rows) per wave
#define WAVES    4
#define ROWS_PER_WAVE  (MT*16)            // 32
#define ROWS_PER_BLOCK (WAVES*ROWS_PER_WAVE) // 128
#define ROWS_TOTAL (32*8192)              // 262144

typedef __attribute__((address_space(1))) const void GV;
typedef __attribute__((address_space(3))) void LV;

__device__ __forceinline__ short f2bf(float f) {
    union { float f; unsigned u; } v; v.f = f;
    unsigned r = v.u + 0x7FFFu + ((v.u >> 16) & 1u);
    return (short)(r >> 16);
}

__device__ __forceinline__ float rcp_fast(float x) {
    return __builtin_amdgcn_rcpf(x);
}

__device__ __forceinline__ float tanh_fast(float x) {
    float e = __expf(2.0f * x);
    return __builtin_fmaf(-2.0f, rcp_fast(e + 1.0f), 1.0f);
}

// Pack We (fp32 [256][512]) into bf16 MFMA B-fragments:
// frag[(nt*8+kt)*64 + lane][j] = We[kt*32 + (lane>>4)*8 + j][nt*16 + (lane&15)]
// => per (nt,kt): 1KB contiguous, lane-linear (perfect for global_load_lds w=16)
__global__ void prepack_B(const float* __restrict__ We, short* __restrict__ Bh) {
    int i = blockIdx.x * 256 + threadIdx.x;      // 131072 elements
    int k = i >> 9;
    int n = i & 511;
    int nt = n >> 4, c = n & 15;
    int kt = k >> 5, g = (k >> 3) & 3, j = k & 7;
    int idx = (((nt * 8 + kt) * 64) + (g * 16 + c)) * 8 + j;
    Bh[idx] = f2bf(We[i]);
}

__global__ __launch_bounds__(256, 5) void softpool_main(
    const float* __restrict__ x, const short* __restrict__ Bh,
    const float* __restrict__ be, const float* __restrict__ Wr,
    const float* __restrict__ br, float* __restrict__ out)
{
    const int lane = threadIdx.x & 63;
    const int wave = threadIdx.x >> 6;
    const int c = lane & 15;     // A row-in-tile / C col / B col
    const int g = lane >> 4;     // k-group
    const long row0 = (long)blockIdx.x * ROWS_PER_BLOCK + (long)wave * ROWS_PER_WAVE;

    __shared__ short Bl[2][4096];   // 2 x 8KB double buffer (one nt-tile each)

    // Each wave stages kt = 2*wave, 2*wave+1 (1KB each) of the nt-tile.
    const int kt0 = wave * 2;
    const short* gB = Bh + (long)kt0 * 512 + lane * 8;   // + nt*4096 (+512 for kt0+1)

    #define STAGE(buf, ntv) {                                                  \
        const short* _g = gB + (long)(ntv) * 4096;                             \
        __builtin_amdgcn_global_load_lds((GV*)_g,                              \
            (LV*)&Bl[buf][kt0 * 512], 16, 0, 0);                               \
        __builtin_amdgcn_global_load_lds((GV*)(_g + 512),                      \
            (LV*)&Bl[buf][kt0 * 512 + 512], 16, 0, 0);                         \
    }

    // Prologue: stage nt=0 into buf0 (issued before the A HBM loads)
    STAGE(0, 0)

    // ---- Load A fragments (2 Mtiles x 8 k-steps), fp32 -> bf16, keep in regs
    bf16x8 a[MT][KT];
    #pragma unroll
    for (int m = 0; m < MT; ++m) {
        const float* xr = x + (row0 + m * 16 + c) * D + g * 8;
        #pragma unroll
        for (int kt = 0; kt < KT; ++kt) {
            float4 v0 = *(const float4*)(xr + kt * 32);
            float4 v1 = *(const float4*)(xr + kt * 32 + 4);
            bf16x8 t;
            t[0] = f2bf(v0.x); t[1] = f2bf(v0.y); t[2] = f2bf(v0.z); t[3] = f2bf(v0.w);
            t[4] = f2bf(v1.x); t[5] = f2bf(v1.y); t[6] = f2bf(v1.z); t[7] = f2bf(v1.w);
            a[m][kt] = t;
        }
    }

    float lp[MT][4];
    #pragma unroll
    for (int m = 0; m < MT; ++m)
        #pragma unroll
        for (int r = 0; r < 4; ++r) lp[m][r] = 0.0f;

    __syncthreads();   // buf0 staged (drains vmcnt)

    #define COMPUTE(buf, ntv) {                                                \
        f32x4 acc[MT];                                                         \
        _Pragma("unroll")                                                      \
        for (int m = 0; m < MT; ++m)                                           \
            _Pragma("unroll")                                                  \
            for (int r = 0; r < 4; ++r) acc[m][r] = 0.0f;                      \
        _Pragma("unroll")                                                      \
        for (int kt = 0; kt < KT; ++kt) {                                      \
            bf16x8 b = *(const bf16x8*)&Bl[buf][kt * 512 + lane * 8];          \
            _Pragma("unroll")                                                  \
            for (int m = 0; m < MT; ++m)                                       \
                acc[m] = __builtin_amdgcn_mfma_f32_16x16x32_bf16(              \
                             a[m][kt], b, acc[m], 0, 0, 0);                    \
        }                                                                      \
        int n = (ntv) * 16 + c;                                                \
        float bias = be[n];                                                    \
        float vr   = Wr[n];                                                    \
        _Pragma("unroll")                                                      \
        for (int m = 0; m < MT; ++m)                                           \
            _Pragma("unroll")                                                  \
            for (int r = 0; r < 4; ++r)                                        \
                lp[m][r] += tanh_fast(acc[m][r] + bias) * vr;                  \
    }

    // ---- Main loop: 2x unrolled, LDS double-buffered B
    for (int nt = 0; nt < NT; nt += 2) {
        STAGE(1, nt + 1)          // issue next-tile loads first (T3 order)
        COMPUTE(0, nt)
        __syncthreads();          // buf1 writes landed; buf0 reads done
        if (nt + 2 < NT) STAGE(0, nt + 2)
        COMPUTE(1, nt + 1)
        __syncthreads();
    }

    // ---- Reduce logits across the 16 cols; softmax(sigmoid); weighted output
    const float brv = br[0];
    #pragma unroll
    for (int m = 0; m < MT; ++m) {
        float l0 = lp[m][0], l1 = lp[m][1], l2 = lp[m][2], l3 = lp[m][3];
        #pragma unroll
        for (int off = 1; off < 16; off <<= 1) {
            l0 += __shfl_xor(l0, off, 64);
            l1 += __shfl_xor(l1, off, 64);
            l2 += __shfl_xor(l2, off, 64);
            l3 += __shfl_xor(l3, off, 64);
        }
        float s0 = rcp_fast(1.0f + __expf(-(l0 + brv)));
        float s1 = rcp_fast(1.0f + __expf(-(l1 + brv)));
        float s2 = rcp_fast(1.0f + __expf(-(l2 + brv)));
        float s3 = rcp_fast(1.0f + __expf(-(l3 + brv)));
        float e0 = __expf(s0), e1 = __expf(s1), e2 = __expf(s2), e3 = __expf(s3);
        float inv = rcp_fast(e0 + e1 + e2 + e3);
        float w0 = e0 * inv, w1 = e1 * inv, w2 = e2 * inv, w3 = e3 * inv;

        const long wrow = row0 + m * 16 + g * 4;
        const long W = wrow >> 2;
        const float* xw = x + wrow * D + c * 4;
        float* op = out + W * D + c * 4;
        #pragma unroll
        for (int q = 0; q < 4; ++q) {
            float4 r0 = *(const float4*)(xw + 0 * D + q * 64);
            float4 r1 = *(const float4*)(xw + 1 * D + q * 64);
            float4 r2 = *(const float4*)(xw + 2 * D + q * 64);
            float4 r3 = *(const float4*)(xw + 3 * D + q * 64);
            float4 oo;
            oo.x = w0 * r0.x + w1 * r1.x + w2 * r2.x + w3 * r3.x;
            oo.y = w0 * r0.y + w1 * r1.y + w2 * r2.y + w3 * r3.y;
            oo.z = w0 * r0.z + w1 * r1.z + w2 * r2.z + w3 * r3.z;
            oo.w = w0 * r0.w + w1 * r1.w + w2 * r2.w + w3 * r3.w;
            *(float4*)(op + q * 64) = oo;
        }
    }
}

extern "C" void kernel_launch(void* const* d_in, const int* in_sizes, int n_in,
                              void* d_out, int out_size, void* d_ws, size_t ws_size,
                              hipStream_t stream) {
    const float* x  = (const float*)d_in[0];
    const float* We = (const float*)d_in[1];
    const float* be = (const float*)d_in[2];
    const float* Wr = (const float*)d_in[3];
    const float* br = (const float*)d_in[4];
    float* out = (float*)d_out;
    short* Bh  = (short*)d_ws;   // 131072 bf16 = 256 KB

    prepack_B<<<NH * D / 256, 256, 0, stream>>>(We, Bh);

    const int blocks = ROWS_TOTAL / ROWS_PER_BLOCK;   // 2048
    softpool_main<<<blocks, 256, 0, stream>>>(x, Bh, be, Wr, br, out);
}